// Round 6
// baseline (430.390 us; speedup 1.0000x reference)
//
#include <hip/hip_runtime.h>
#include <hip/hip_bf16.h>
#include <stdint.h>

#define P_TOT   4096
#define N_CODE  16384
#define DIM     256
#define HW      1024
#define CHW     262144
#define NBLK    16        // 16384 / 1024 (per-wg nb-chunk = 4 panels of 256)

typedef unsigned long long u64;
typedef unsigned short u16;
typedef __attribute__((ext_vector_type(4))) float f32x4;
typedef __attribute__((ext_vector_type(8))) short bf16x8;
typedef __attribute__((ext_vector_type(8))) unsigned short ushort8;

#define FENCE() asm volatile("" ::: "memory")
#define BAR()   __builtin_amdgcn_s_barrier()
#define VM(n)   asm volatile("s_waitcnt vmcnt(" #n ")" ::: "memory")

__device__ __forceinline__ unsigned int mono(float f) {
  unsigned int u = __float_as_uint(f);
  return (u & 0x80000000u) ? ~u : (u | 0x80000000u);
}
__device__ __forceinline__ u16 f2bf(float f) {
  __hip_bfloat16 h = __float2bfloat16(f);
  return *(u16*)&h;
}
__device__ __forceinline__ float bf2f(u16 b) {
  __hip_bfloat16 h = *(__hip_bfloat16*)&b;
  return __bfloat162float(h);
}
__device__ __forceinline__ void gload16(const void* g, void* l) {
  __builtin_amdgcn_global_load_lds(
      (const __attribute__((address_space(1))) unsigned int*)g,
      (__attribute__((address_space(3))) unsigned int*)l, 16, 0, 0);
}

// ================== merged prep: split_cb | split_x | cnorm | wt ==================
// bfrag unit [(nb*8+kt)*4+bq] of 4096 u16: [h(2)][s(4)][row64][8elem]
// xfrag unit [(mbO*8+kt)*4+aq] same internal layout (rows = pixels)
__global__ __launch_bounds__(256) void k_prep(const float* __restrict__ cb,
                                              const float* __restrict__ latent,
                                              const float* __restrict__ dec_w,
                                              u16* __restrict__ bfrag,
                                              u16* __restrict__ xfrag,
                                              float* __restrict__ cnorm,
                                              float* __restrict__ wt) {
  __shared__ float ls[64][68];
  int bid = blockIdx.x;
  int t = threadIdx.x;
  if (bid < 1024) {
    // ---- codebook -> fragment-linear bf16 hi/lo ----
    int blk = bid;                   // nb(64) x bq(4) x kp(4)
    int kp = blk & 3, bq = (blk >> 2) & 3, nb = blk >> 4;
    int code0 = nb * 256 + bq * 64;
    int k0 = kp * 64;
    int lr = t >> 4, lc = (t & 15) * 4;
    #pragma unroll
    for (int pss = 0; pss < 4; ++pss) {
      int row = pss * 16 + lr;
      float4 v = *(const float4*)&cb[(size_t)(code0 + row) * DIM + k0 + lc];
      ls[row][lc] = v.x; ls[row][lc + 1] = v.y; ls[row][lc + 2] = v.z; ls[row][lc + 3] = v.w;
    }
    __syncthreads();
    int row64 = t & 63, g = t >> 6;
    #pragma unroll
    for (int it = 0; it < 4; ++it) {
      int combo = it * 4 + g;        // kt2*8 + s*2 + h
      int kt2 = combo >> 3, s = (combo >> 1) & 3, h = combo & 1;
      int kt = kp * 2 + kt2;
      ushort8 o;
      #pragma unroll
      for (int e = 0; e < 8; ++e) {
        float x = ls[row64][kt2 * 32 + s * 8 + e];
        u16 hi = f2bf(x);
        o[e] = h ? f2bf(x - bf2f(hi)) : hi;
      }
      size_t unitIdx = (size_t)(nb * 8 + kt) * 4 + bq;
      *(ushort8*)&bfrag[unitIdx * 4096 + (size_t)((h * 4 + s) * 64 + row64) * 8] = o;
    }
  } else if (bid < 1280) {
    // ---- latent NCHW -> fragment-linear bf16 hi/lo (rows = pixels) ----
    int blk = bid - 1024;            // rowblk(64) x kp(4)
    int kp = blk & 3, rowblk = blk >> 2;
    int g0 = rowblk * 64;
    int b = g0 >> 10, hw0 = g0 & 1023;
    int c0 = kp * 64;
    int ch = t >> 4, px4 = (t & 15) * 4;
    #pragma unroll
    for (int pss = 0; pss < 4; ++pss) {
      int c = pss * 16 + ch;
      float4 v = *(const float4*)&latent[(size_t)b * CHW + (size_t)(c0 + c) * HW + hw0 + px4];
      ls[px4 + 0][c] = v.x; ls[px4 + 1][c] = v.y; ls[px4 + 2][c] = v.z; ls[px4 + 3][c] = v.w;
    }
    __syncthreads();
    int row64 = t & 63, g = t >> 6;
    #pragma unroll
    for (int it = 0; it < 4; ++it) {
      int combo = it * 4 + g;
      int kt2 = combo >> 3, s = (combo >> 1) & 3, h = combo & 1;
      int kt = kp * 2 + kt2;
      ushort8 o;
      #pragma unroll
      for (int e = 0; e < 8; ++e) {
        float x = ls[row64][kt2 * 32 + s * 8 + e];
        u16 hi = f2bf(x);
        o[e] = h ? f2bf(x - bf2f(hi)) : hi;
      }
      int mbO = rowblk >> 2, aq = rowblk & 3;
      size_t unitIdx = (size_t)(mbO * 8 + kt) * 4 + aq;
      *(ushort8*)&xfrag[unitIdx * 4096 + (size_t)((h * 4 + s) * 64 + row64) * 8] = o;
    }
  } else if (bid < 5376) {
    // ---- codebook squared norms ----
    int code = (bid - 1280) * 4 + (t >> 6);
    int lane = t & 63;
    float4 v = ((const float4*)(cb + (size_t)code * DIM))[lane];
    float sv = fmaf(v.x, v.x, fmaf(v.y, v.y, fmaf(v.z, v.z, v.w * v.w)));
    #pragma unroll
    for (int off = 32; off; off >>= 1) sv += __shfl_down(sv, off, 64);
    if (lane == 0) cnorm[code] = sv;
  } else {
    // ---- dec_w transpose -> [oc][ky][kx][256] ----
    int e = (bid - 5376) * 256 + t;
    if (e < 6912) {
      int ic = e & 255; int r = e >> 8;
      int kx = r % 3; r /= 3; int ky = r % 3; int oc = r / 3;
      wt[e] = dec_w[((oc * 256 + ic) * 3 + ky) * 3 + kx];
    }
  }
}

// ================== main VQ: BM=128, A-in-regs, B-LDS dbuf, 64-phase pipeline ==================
__global__ __launch_bounds__(512, 4) void k_vq(const u16* __restrict__ xfrag,
                                               const u16* __restrict__ bfrag,
                                               const float* __restrict__ cnorm,
                                               u64* __restrict__ partial) {
  __shared__ u16 bbuf[2][4][4096];   // 64 KB double-buffered B K-tile (256 codes x 32k x hi/lo)
  __shared__ float cnl[1024];        // cnorm chunk for this wg's 4 panels

  int bid = blockIdx.x;              // 512 wgs = 2 per CU
  int xcd = bid & 7, ix = bid >> 3;
  int nbc = xcd * 2 + (ix >> 5);     // 0..15  (2 nbc per XCD -> 2MB B in L2)
  int mb  = ix & 31;                 // 0..31  (128-row X block)

  int tid = threadIdx.x, lane = tid & 63, w = tid >> 6;
  int fr = lane & 15, s = lane >> 4;
  int tid8 = tid * 8;

  const u16* Bb = bfrag + (size_t)nbc * 32 * 16384;   // 32 tiles x 4 units x 4096 u16

  // ---- prologue: stage tile 0, A->regs, cnorm->LDS, full drain ----
  #pragma unroll
  for (int r = 0; r < 4; ++r)
    gload16(Bb + (size_t)r * 4096 + tid8, &bbuf[0][r][0] + tid8);

  int rowg = mb * 128 + w * 16;
  int mbO = rowg >> 8, aq = (rowg >> 6) & 3, rb = rowg & 63;
  bf16x8 ah[8], al[8];
  #pragma unroll
  for (int kt = 0; kt < 8; ++kt) {
    const u16* ub = xfrag + ((size_t)(mbO * 8 + kt) * 4 + aq) * 4096;
    ah[kt] = *(const bf16x8*)&ub[(size_t)((0 + s) * 64 + rb + fr) * 8];
    al[kt] = *(const bf16x8*)&ub[(size_t)((4 + s) * 64 + rb + fr) * 8];
  }
  cnl[tid]       = cnorm[nbc * 1024 + tid];
  cnl[tid + 512] = cnorm[nbc * 1024 + 512 + tid];
  __syncthreads();                   // drains all vmem; bbuf[0] + cnl ready

  f32x4 acc[16] = {};
  u64 best[4] = {~0ull, ~0ull, ~0ull, ~0ull};
  bf16x8 bh[8], bl[8];

  #define READ8(buf, half)                                                    \
    _Pragma("unroll")                                                         \
    for (int j = 0; j < 8; ++j) {                                             \
      const int jj = (half) * 8 + j;                                          \
      const u16* bp = &bbuf[buf][jj >> 2][0];                                 \
      bh[j] = *(const bf16x8*)&bp[(size_t)((0 + s) * 64 + (jj & 3) * 16 + fr) * 8]; \
      bl[j] = *(const bf16x8*)&bp[(size_t)((4 + s) * 64 + (jj & 3) * 16 + fr) * 8]; \
    }
  #define MFMA8(kt, half)                                                     \
    __builtin_amdgcn_s_setprio(1);                                            \
    _Pragma("unroll")                                                         \
    for (int j = 0; j < 8; ++j)                                               \
      acc[(half) * 8 + j] = __builtin_amdgcn_mfma_f32_16x16x32_bf16(ah[kt], bh[j], acc[(half) * 8 + j], 0, 0, 0); \
    _Pragma("unroll")                                                         \
    for (int j = 0; j < 8; ++j)                                               \
      acc[(half) * 8 + j] = __builtin_amdgcn_mfma_f32_16x16x32_bf16(ah[kt], bl[j], acc[(half) * 8 + j], 0, 0, 0); \
    _Pragma("unroll")                                                         \
    for (int j = 0; j < 8; ++j)                                               \
      acc[(half) * 8 + j] = __builtin_amdgcn_mfma_f32_16x16x32_bf16(al[kt], bh[j], acc[(half) * 8 + j], 0, 0, 0); \
    __builtin_amdgcn_s_setprio(0);
  #define STAGE2(nxt, base, u0)                                               \
    gload16((base) + (size_t)(u0) * 4096 + tid8, &bbuf[nxt][(u0)][0] + tid8); \
    gload16((base) + (size_t)((u0) + 1) * 4096 + tid8, &bbuf[nxt][(u0) + 1][0] + tid8);
  #define FOLD(pp)                                                            \
    _Pragma("unroll")                                                         \
    for (int jj = 0; jj < 16; ++jj) {                                         \
      float cnv = cnl[(pp) * 256 + jj * 16 + fr];                             \
      unsigned code = (unsigned)(nbc * 1024 + (pp) * 256 + jj * 16 + fr);     \
      _Pragma("unroll")                                                       \
      for (int r = 0; r < 4; ++r) {                                           \
        float val = fmaf(-2.0f, acc[jj][r], cnv);                             \
        u64 key = ((u64)mono(val) << 32) | code;                              \
        if (key < best[r]) best[r] = key;                                     \
        acc[jj][r] = 0.0f;                                                    \
      }                                                                       \
    }

  // ---- 4 panels x 8 K-tiles = 64 phases, seamless counted-vmcnt pipeline ----
  #pragma unroll 1
  for (int p = 0; p < 4; ++p) {
    #pragma unroll
    for (int kt = 0; kt < 8; ++kt) {
      const int cur = kt & 1, nxt = cur ^ 1;
      const u16* SB = Bb + (size_t)(p * 8 + kt + 1) * 16384;
      if (kt < 7) {
        // ---- steady phases ----
        READ8(cur, 0);
        STAGE2(nxt, SB, 0);
        BAR();
        MFMA8(kt, 0);
        VM(2); BAR(); FENCE();
        READ8(cur, 1);
        STAGE2(nxt, SB, 2);
        BAR();
        MFMA8(kt, 1);
        VM(2); BAR(); FENCE();
      } else {
        // ---- kt==7: panel boundary (tile 31 = global tail) ----
        bool last = (p == 3);
        READ8(cur, 0);
        if (!last) { STAGE2(nxt, SB, 0); }
        BAR();
        MFMA8(kt, 0);
        if (!last) { VM(2); } else { VM(0); }
        BAR(); FENCE();
        READ8(cur, 1);
        if (!last) { STAGE2(nxt, SB, 2); }
        BAR();
        MFMA8(kt, 1);
        FOLD(p);
        if (!last) { VM(2); }
        BAR(); FENCE();
      }
    }
  }

  // ---- reduce best over fr lanes (codes), write per-row minimum ----
  #pragma unroll
  for (int d = 1; d < 16; d <<= 1) {
    #pragma unroll
    for (int r = 0; r < 4; ++r) {
      u64 o = __shfl_xor(best[r], d, 64);
      if (o < best[r]) best[r] = o;
    }
  }
  if (fr == 0) {
    int rowb = mb * 128 + w * 16 + s * 4;
    #pragma unroll
    for (int r = 0; r < 4; ++r)
      partial[(size_t)(rowb + r) * NBLK + nbc] = best[r];
  }
}

// ---- per-row top-2 reduce + exact fp64 refinement -> final index ----
__global__ __launch_bounds__(64) void k_reduce(const u64* __restrict__ partial,
                                               const float* __restrict__ latent,
                                               const float* __restrict__ cb,
                                               int* __restrict__ idxo) {
  int p = blockIdx.x;
  int t = threadIdx.x;
  u64 v = (t < NBLK) ? partial[(size_t)p * NBLK + t] : ~0ull;
  u64 m1 = v;
  #pragma unroll
  for (int d = 1; d < 64; d <<= 1) { u64 o = __shfl_xor(m1, d, 64); if (o < m1) m1 = o; }
  u64 vv = (v == m1) ? ~0ull : v;
  u64 m2 = vv;
  #pragma unroll
  for (int d = 1; d < 64; d <<= 1) { u64 o = __shfl_xor(m2, d, 64); if (o < m2) m2 = o; }
  int n1 = (int)(m1 & 0xFFFFFFFFull);
  int n2 = (int)(m2 & 0xFFFFFFFFull);

  int b = p >> 10, hw = p & 1023;
  const float* xb = latent + (size_t)b * CHW + hw;
  double d1 = 0.0, d2 = 0.0;
  #pragma unroll
  for (int q = 0; q < 4; ++q) {
    int c = t * 4 + q;
    double xv = (double)xb[(size_t)c * HW];
    double e1 = xv - (double)cb[(size_t)n1 * DIM + c]; d1 += e1 * e1;
    double e2 = xv - (double)cb[(size_t)n2 * DIM + c]; d2 += e2 * e2;
  }
  #pragma unroll
  for (int d = 32; d; d >>= 1) {
    d1 += __shfl_down(d1, d, 64);
    d2 += __shfl_down(d2, d, 64);
  }
  if (t == 0) {
    idxo[p] = (d2 < d1 || (d2 == d1 && n2 < n1)) ? n2 : n1;
  }
}

// ---- gather + 3x3 conv + bias + (x+1)*0.5 + clamp ----
__global__ __launch_bounds__(256) void k_conv(const float* __restrict__ cb,
                                              const int* __restrict__ idx,
                                              const float* __restrict__ wt,
                                              const float* __restrict__ bias,
                                              float* __restrict__ out) {
  int y = blockIdx.x, b = blockIdx.y;
  int t = threadIdx.x;
  int x = t & 31, icg = t >> 5;
  float a0 = 0.f, a1 = 0.f, a2 = 0.f;
  #pragma unroll
  for (int dy = -1; dy <= 1; dy++) {
    int yy = y + dy;
    if (yy < 0 || yy >= 32) continue;
    #pragma unroll
    for (int dx = -1; dx <= 1; dx++) {
      int xx = x + dx;
      if (xx < 0 || xx >= 32) continue;
      int n = idx[b * HW + yy * 32 + xx];
      const float4* crow = (const float4*)(cb + (size_t)n * DIM + icg * 32);
      int tap = (dy + 1) * 3 + (dx + 1);
      const float4* w0 = (const float4*)(wt + (size_t)(0 * 9 + tap) * DIM + icg * 32);
      const float4* w1 = (const float4*)(wt + (size_t)(1 * 9 + tap) * DIM + icg * 32);
      const float4* w2 = (const float4*)(wt + (size_t)(2 * 9 + tap) * DIM + icg * 32);
      #pragma unroll
      for (int q = 0; q < 8; q++) {
        float4 qv = crow[q];
        float4 wa = w0[q];
        a0 = fmaf(qv.x, wa.x, a0); a0 = fmaf(qv.y, wa.y, a0);
        a0 = fmaf(qv.z, wa.z, a0); a0 = fmaf(qv.w, wa.w, a0);
        float4 wb = w1[q];
        a1 = fmaf(qv.x, wb.x, a1); a1 = fmaf(qv.y, wb.y, a1);
        a1 = fmaf(qv.z, wb.z, a1); a1 = fmaf(qv.w, wb.w, a1);
        float4 wcv = w2[q];
        a2 = fmaf(qv.x, wcv.x, a2); a2 = fmaf(qv.y, wcv.y, a2);
        a2 = fmaf(qv.z, wcv.z, a2); a2 = fmaf(qv.w, wcv.w, a2);
      }
    }
  }
  __shared__ float red[3][32][8];
  red[0][x][icg] = a0; red[1][x][icg] = a1; red[2][x][icg] = a2;
  __syncthreads();
  if (t < 96) {
    int oc = t >> 5, xo = t & 31;
    float sum = 0.f;
    #pragma unroll
    for (int k = 0; k < 8; k++) sum += red[oc][xo][k];
    sum += bias[oc];
    sum = (sum + 1.0f) * 0.5f;
    sum = fminf(fmaxf(sum, 0.0f), 1.0f);
    out[((size_t)(b * 3 + oc) * 32 + y) * 32 + xo] = sum;
  }
}

extern "C" void kernel_launch(void* const* d_in, const int* in_sizes, int n_in,
                              void* d_out, int out_size, void* d_ws, size_t ws_size,
                              hipStream_t stream) {
  const float* latent = (const float*)d_in[0];   // [4,256,32,32]
  const float* cb     = (const float*)d_in[1];   // [16384,256]
  const float* dec_w  = (const float*)d_in[2];   // [3,256,3,3]
  const float* dec_b  = (const float*)d_in[3];   // [3]
  float* out = (float*)d_out;                    // [4,3,32,32]

  char* ws = (char*)d_ws;
  u64*   partial = (u64*)ws;                      // 512 KB [4096][16]
  float* cnorm   = (float*)(ws + 0x080000);       // 64 KB
  int*   idx     = (int*)  (ws + 0x090000);       // 16 KB
  float* wt      = (float*)(ws + 0x094000);       // 27 KB
  u16*   xfrag   = (u16*)  (ws + 0x100000);       // 4 MB
  u16*   bfrag   = (u16*)  (ws + 0x800000);       // 16 MB (ends at 24 MB)

  k_prep  <<<dim3(5403), dim3(256), 0, stream>>>(cb, latent, dec_w, bfrag, xfrag, cnorm, wt);
  k_vq    <<<dim3(512),  dim3(512), 0, stream>>>(xfrag, bfrag, cnorm, partial);
  k_reduce<<<dim3(P_TOT), dim3(64), 0, stream>>>(partial, latent, cb, idx);
  k_conv  <<<dim3(32, 4), dim3(256), 0, stream>>>(cb, idx, wt, dec_b, out);
}

// Round 8
// 216.948 us; speedup vs baseline: 1.9838x; 1.9838x over previous
//
#include <hip/hip_runtime.h>
#include <hip/hip_bf16.h>
#include <stdint.h>

#define P_TOT   4096
#define N_CODE  16384
#define DIM     256
#define HW      1024
#define CHW     262144
#define NBLK    16        // 16384 / 1024 codes per wg-chunk

typedef unsigned long long u64;
typedef unsigned short u16;
typedef __attribute__((ext_vector_type(4))) float f32x4;
typedef __attribute__((ext_vector_type(8))) short bf16x8;
typedef __attribute__((ext_vector_type(8))) unsigned short ushort8;

#define FENCE() asm volatile("" ::: "memory")
#define BAR()   __builtin_amdgcn_s_barrier()
#define VM(n)   asm volatile("s_waitcnt vmcnt(" #n ")" ::: "memory")

__device__ __forceinline__ unsigned int mono(float f) {
  unsigned int u = __float_as_uint(f);
  return (u & 0x80000000u) ? ~u : (u | 0x80000000u);
}
__device__ __forceinline__ u16 f2bf(float f) {
  __hip_bfloat16 h = __float2bfloat16(f);
  return *(u16*)&h;
}
__device__ __forceinline__ float bf2f(u16 b) {
  __hip_bfloat16 h = *(__hip_bfloat16*)&b;
  return __bfloat162float(h);
}
__device__ __forceinline__ void gload16(const void* g, void* l) {
  __builtin_amdgcn_global_load_lds(
      (const __attribute__((address_space(1))) unsigned int*)g,
      (__attribute__((address_space(3))) unsigned int*)l, 16, 0, 0);
}

// ================== merged prep: split_cb | split_x | cnorm | wt ==================
// bfrag unit [(nb*8+kt)*4+bq] of 4096 u16: [h(2)][s(4)][row64][8elem]
// xfrag unit [(mbO*8+kt)*4+aq] same internal layout (rows = pixels)
__global__ __launch_bounds__(256) void k_prep(const float* __restrict__ cb,
                                              const float* __restrict__ latent,
                                              const float* __restrict__ dec_w,
                                              u16* __restrict__ bfrag,
                                              u16* __restrict__ xfrag,
                                              float* __restrict__ cnorm,
                                              float* __restrict__ wt) {
  __shared__ float ls[64][68];
  int bid = blockIdx.x;
  int t = threadIdx.x;
  if (bid < 1024) {
    int blk = bid;                   // nb(64) x bq(4) x kp(4)
    int kp = blk & 3, bq = (blk >> 2) & 3, nb = blk >> 4;
    int code0 = nb * 256 + bq * 64;
    int k0 = kp * 64;
    int lr = t >> 4, lc = (t & 15) * 4;
    #pragma unroll
    for (int pss = 0; pss < 4; ++pss) {
      int row = pss * 16 + lr;
      float4 v = *(const float4*)&cb[(size_t)(code0 + row) * DIM + k0 + lc];
      ls[row][lc] = v.x; ls[row][lc + 1] = v.y; ls[row][lc + 2] = v.z; ls[row][lc + 3] = v.w;
    }
    __syncthreads();
    int row64 = t & 63, g = t >> 6;
    #pragma unroll
    for (int it = 0; it < 4; ++it) {
      int combo = it * 4 + g;        // kt2*8 + s*2 + h
      int kt2 = combo >> 3, s = (combo >> 1) & 3, h = combo & 1;
      int kt = kp * 2 + kt2;
      ushort8 o;
      #pragma unroll
      for (int e = 0; e < 8; ++e) {
        float x = ls[row64][kt2 * 32 + s * 8 + e];
        u16 hi = f2bf(x);
        o[e] = h ? f2bf(x - bf2f(hi)) : hi;
      }
      size_t unitIdx = (size_t)(nb * 8 + kt) * 4 + bq;
      *(ushort8*)&bfrag[unitIdx * 4096 + (size_t)((h * 4 + s) * 64 + row64) * 8] = o;
    }
  } else if (bid < 1280) {
    int blk = bid - 1024;            // rowblk(64) x kp(4)
    int kp = blk & 3, rowblk = blk >> 2;
    int g0 = rowblk * 64;
    int b = g0 >> 10, hw0 = g0 & 1023;
    int c0 = kp * 64;
    int ch = t >> 4, px4 = (t & 15) * 4;
    #pragma unroll
    for (int pss = 0; pss < 4; ++pss) {
      int c = pss * 16 + ch;
      float4 v = *(const float4*)&latent[(size_t)b * CHW + (size_t)(c0 + c) * HW + hw0 + px4];
      ls[px4 + 0][c] = v.x; ls[px4 + 1][c] = v.y; ls[px4 + 2][c] = v.z; ls[px4 + 3][c] = v.w;
    }
    __syncthreads();
    int row64 = t & 63, g = t >> 6;
    #pragma unroll
    for (int it = 0; it < 4; ++it) {
      int combo = it * 4 + g;
      int kt2 = combo >> 3, s = (combo >> 1) & 3, h = combo & 1;
      int kt = kp * 2 + kt2;
      ushort8 o;
      #pragma unroll
      for (int e = 0; e < 8; ++e) {
        float x = ls[row64][kt2 * 32 + s * 8 + e];
        u16 hi = f2bf(x);
        o[e] = h ? f2bf(x - bf2f(hi)) : hi;
      }
      int mbO = rowblk >> 2, aq = rowblk & 3;
      size_t unitIdx = (size_t)(mbO * 8 + kt) * 4 + aq;
      *(ushort8*)&xfrag[unitIdx * 4096 + (size_t)((h * 4 + s) * 64 + row64) * 8] = o;
    }
  } else if (bid < 5376) {
    int code = (bid - 1280) * 4 + (t >> 6);
    int lane = t & 63;
    float4 v = ((const float4*)(cb + (size_t)code * DIM))[lane];
    float sv = fmaf(v.x, v.x, fmaf(v.y, v.y, fmaf(v.z, v.z, v.w * v.w)));
    #pragma unroll
    for (int off = 32; off; off >>= 1) sv += __shfl_down(sv, off, 64);
    if (lane == 0) cnorm[code] = sv;
  } else {
    int e = (bid - 5376) * 256 + t;
    if (e < 6912) {
      int ic = e & 255; int r = e >> 8;
      int kx = r % 3; r /= 3; int ky = r % 3; int oc = r / 3;
      wt[e] = dec_w[((oc * 256 + ic) * 3 + ky) * 3 + kx];
    }
  }
}

// ================== main VQ: 256x256 tile, 2 phases/K-tile, 32-tile seamless pipeline ==================
// Grid 256 = 1 wg/CU. Each wg: 4 nb-panels (1024 codes) x 8 K-tiles.
__global__ __launch_bounds__(512, 2) void k_vq(const u16* __restrict__ xfrag,
                                               const u16* __restrict__ bfrag,
                                               const float* __restrict__ cnorm,
                                               u64* __restrict__ partial) {
  __shared__ u16 lds[2][2][4][4096];   // [buf][A/B][unit][8KB] = 128 KiB
  __shared__ float cnl[1024];

  int bid = blockIdx.x;                // 256 wgs
  int xcd = bid & 7, ix = bid >> 3;    // 32 per XCD
  int nbc = xcd * 2 + (ix >> 4);       // 0..15 (1024-code chunk; 2 chunks/XCD -> 2MB B in L2)
  int mb  = ix & 15;                   // 0..15 (256-row X block)

  int tid = threadIdx.x, lane = tid & 63, w = tid >> 6;
  int fr = lane & 15, s = lane >> 4;
  int aq = w >> 1;
  int rbase = (w & 1) * 32;
  int tid8 = tid * 8;

  const u16* Xb = xfrag + (size_t)mb * 32 * 4096;    // units kt*4+aq
  const u16* Bb = bfrag + (size_t)nbc * 128 * 4096;  // 32 tiles x 4 units

  // cnorm chunk -> LDS (completes before any gload_lds issues)
  cnl[tid]       = cnorm[nbc * 1024 + tid];
  cnl[tid + 512] = cnorm[nbc * 1024 + 512 + tid];
  __syncthreads();

  // ---- prologue: stage tile 0 (A0..A3, B0, B1, then B2, B3) ----
  #pragma unroll
  for (int r = 0; r < 4; ++r) gload16(Xb + (size_t)r * 4096 + tid8, &lds[0][0][r][0] + tid8);
  gload16(Bb + (size_t)0 * 4096 + tid8, &lds[0][1][0][0] + tid8);
  gload16(Bb + (size_t)1 * 4096 + tid8, &lds[0][1][1][0] + tid8);
  gload16(Bb + (size_t)2 * 4096 + tid8, &lds[0][1][2][0] + tid8);
  gload16(Bb + (size_t)3 * 4096 + tid8, &lds[0][1][3][0] + tid8);
  VM(2); BAR(); FENCE();               // A+B0,B1 ready; B2,B3 in flight

  f32x4 acc[2][16] = {};
  u64 best[4]  = {~0ull, ~0ull, ~0ull, ~0ull};   // best for m=0 rows
  u64 best2[4] = {~0ull, ~0ull, ~0ull, ~0ull};   // best for m=1 rows
  bf16x8 ah[2], al[2], bh[4], bl[4];

  #define READ_A(LA)                                                          \
    _Pragma("unroll")                                                         \
    for (int m = 0; m < 2; ++m) {                                             \
      ah[m] = *(const bf16x8*)&(LA)[aq * 4096 + (size_t)((0 + s) * 64 + rbase + m * 16 + fr) * 8]; \
      al[m] = *(const bf16x8*)&(LA)[aq * 4096 + (size_t)((4 + s) * 64 + rbase + m * 16 + fr) * 8]; \
    }
  #define READ_B(LB, q)                                                       \
    _Pragma("unroll")                                                         \
    for (int j = 0; j < 4; ++j) {                                             \
      bh[j] = *(const bf16x8*)&(LB)[(q) * 4096 + (size_t)((0 + s) * 64 + j * 16 + fr) * 8]; \
      bl[j] = *(const bf16x8*)&(LB)[(q) * 4096 + (size_t)((4 + s) * 64 + j * 16 + fr) * 8]; \
    }
  #define MFMAQ(q)                                                            \
    __builtin_amdgcn_s_setprio(1);                                            \
    _Pragma("unroll")                                                         \
    for (int m = 0; m < 2; ++m) {                                             \
      _Pragma("unroll")                                                       \
      for (int j = 0; j < 4; ++j)                                             \
        acc[m][(q) * 4 + j] = __builtin_amdgcn_mfma_f32_16x16x32_bf16(ah[m], bh[j], acc[m][(q) * 4 + j], 0, 0, 0); \
    }                                                                         \
    _Pragma("unroll")                                                         \
    for (int m = 0; m < 2; ++m) {                                             \
      _Pragma("unroll")                                                       \
      for (int j = 0; j < 4; ++j)                                             \
        acc[m][(q) * 4 + j] = __builtin_amdgcn_mfma_f32_16x16x32_bf16(ah[m], bl[j], acc[m][(q) * 4 + j], 0, 0, 0); \
    }                                                                         \
    _Pragma("unroll")                                                         \
    for (int m = 0; m < 2; ++m) {                                             \
      _Pragma("unroll")                                                       \
      for (int j = 0; j < 4; ++j)                                             \
        acc[m][(q) * 4 + j] = __builtin_amdgcn_mfma_f32_16x16x32_bf16(al[m], bh[j], acc[m][(q) * 4 + j], 0, 0, 0); \
    }                                                                         \
    __builtin_amdgcn_s_setprio(0);
  #define FOLD(pp)                                                            \
    _Pragma("unroll")                                                         \
    for (int n = 0; n < 16; ++n) {                                            \
      float cnv = cnl[(pp) * 256 + n * 16 + fr];                              \
      unsigned code = (unsigned)(nbc * 1024 + (pp) * 256 + n * 16 + fr);      \
      _Pragma("unroll")                                                       \
      for (int r = 0; r < 4; ++r) {                                           \
        float v0 = fmaf(-2.0f, acc[0][n][r], cnv);                            \
        u64 k0 = ((u64)mono(v0) << 32) | code;                                \
        if (k0 < best[r]) best[r] = k0;                                       \
        acc[0][n][r] = 0.0f;                                                  \
        float v1 = fmaf(-2.0f, acc[1][n][r], cnv);                            \
        u64 k1 = ((u64)mono(v1) << 32) | code;                                \
        if (k1 < best2[r]) best2[r] = k1;                                     \
        acc[1][n][r] = 0.0f;                                                  \
      }                                                                       \
    }

  // ---- 32 K-tiles (4 panels x 8), 2 phases each ----
  #pragma unroll 1
  for (int tt = 0; tt < 32; ++tt) {
    const int cur = tt & 1, nxt = cur ^ 1;
    const int kt = tt & 7;
    u16* LA = &lds[cur][0][0][0];
    u16* LB = &lds[cur][1][0][0];
    const u16* SA = Xb + (size_t)((tt + 1) & 7) * 16384;
    const u16* SB = Bb + (size_t)(tt + 1) * 16384;
    const bool stage = (tt < 31);
    // ---- phase 0: quads 0,1 ----
    READ_A(LA); READ_B(LB, 0);
    if (stage) {
      #pragma unroll
      for (int r = 0; r < 4; ++r) gload16(SA + (size_t)r * 4096 + tid8, &lds[nxt][0][r][0] + tid8);
      gload16(SB + (size_t)0 * 4096 + tid8, &lds[nxt][1][0][0] + tid8);
      gload16(SB + (size_t)1 * 4096 + tid8, &lds[nxt][1][1][0] + tid8);
    }
    BAR();
    MFMAQ(0);
    READ_B(LB, 1);
    MFMAQ(1);
    if (stage) { VM(6); } else { VM(0); }
    BAR(); FENCE();
    // ---- phase 1: quads 2,3 ----
    READ_B(LB, 2);
    if (stage) {
      gload16(SB + (size_t)2 * 4096 + tid8, &lds[nxt][1][2][0] + tid8);
      gload16(SB + (size_t)3 * 4096 + tid8, &lds[nxt][1][3][0] + tid8);
    }
    BAR();
    MFMAQ(2);
    READ_B(LB, 3);
    MFMAQ(3);
    if (kt == 7) { FOLD(tt >> 3); }
    if (stage) { VM(2); }
    BAR(); FENCE();
  }

  // ---- reduce over fr lanes (codes), write per-row minimum ----
  #pragma unroll
  for (int d = 1; d < 16; d <<= 1) {
    #pragma unroll
    for (int r = 0; r < 4; ++r) {
      u64 o = __shfl_xor(best[r], d, 64);
      if (o < best[r]) best[r] = o;
      u64 o2 = __shfl_xor(best2[r], d, 64);
      if (o2 < best2[r]) best2[r] = o2;
    }
  }
  if (fr == 0) {
    int rowb = mb * 256 + w * 32 + s * 4;
    #pragma unroll
    for (int r = 0; r < 4; ++r) {
      partial[(size_t)(rowb + r) * NBLK + nbc] = best[r];
      partial[(size_t)(rowb + 16 + r) * NBLK + nbc] = best2[r];
    }
  }
}

// ---- fused: per-pixel top-2 reduce + fp64 refine (rows y-1..y+1) then 3x3 conv ----
__global__ __launch_bounds__(256) void k_conv(const u64* __restrict__ partial,
                                              const float* __restrict__ latent,
                                              const float* __restrict__ cb,
                                              const float* __restrict__ wt,
                                              const float* __restrict__ bias,
                                              float* __restrict__ out) {
  __shared__ int idxl[3][32];
  int y = blockIdx.x, b = blockIdx.y;
  int t = threadIdx.x;
  int px = t >> 3, sub = t & 7;
  #pragma unroll 1
  for (int r = 0; r < 3; ++r) {
    int yy = min(max(y + r - 1, 0), 31);
    int p = b * HW + yy * 32 + px;
    u64 v0 = partial[(size_t)p * NBLK + sub];
    u64 v1 = partial[(size_t)p * NBLK + 8 + sub];
    u64 m1 = v0 < v1 ? v0 : v1;
    #pragma unroll
    for (int d = 1; d < 8; d <<= 1) { u64 o = __shfl_xor(m1, d, 64); if (o < m1) m1 = o; }
    u64 w0 = (v0 == m1) ? ~0ull : v0;
    u64 w1 = (v1 == m1) ? ~0ull : v1;
    u64 m2 = w0 < w1 ? w0 : w1;
    #pragma unroll
    for (int d = 1; d < 8; d <<= 1) { u64 o = __shfl_xor(m2, d, 64); if (o < m2) m2 = o; }
    int n1 = (int)(m1 & 0xFFFFFFFFull);
    int n2 = (int)(m2 & 0xFFFFFFFFull);
    const float* xb = latent + (size_t)b * CHW + yy * 32 + px;
    double d1 = 0.0, d2 = 0.0;
    #pragma unroll
    for (int q = 0; q < 32; ++q) {
      int c = sub * 32 + q;
      double xv = (double)xb[(size_t)c * HW];
      double e1 = xv - (double)cb[(size_t)n1 * DIM + c]; d1 += e1 * e1;
      double e2 = xv - (double)cb[(size_t)n2 * DIM + c]; d2 += e2 * e2;
    }
    #pragma unroll
    for (int d = 1; d < 8; d <<= 1) { d1 += __shfl_xor(d1, d, 64); d2 += __shfl_xor(d2, d, 64); }
    if (sub == 0) idxl[r][px] = (d2 < d1 || (d2 == d1 && n2 < n1)) ? n2 : n1;
  }
  __syncthreads();

  int x = t & 31, icg = t >> 5;
  float a0 = 0.f, a1 = 0.f, a2 = 0.f;
  #pragma unroll
  for (int dy = -1; dy <= 1; dy++) {
    int yy = y + dy;
    if (yy < 0 || yy >= 32) continue;
    #pragma unroll
    for (int dx = -1; dx <= 1; dx++) {
      int xx = x + dx;
      if (xx < 0 || xx >= 32) continue;
      int n = idxl[dy + 1][xx];
      const float4* crow = (const float4*)(cb + (size_t)n * DIM + icg * 32);
      int tap = (dy + 1) * 3 + (dx + 1);
      const float4* w0p = (const float4*)(wt + (size_t)(0 * 9 + tap) * DIM + icg * 32);
      const float4* w1p = (const float4*)(wt + (size_t)(1 * 9 + tap) * DIM + icg * 32);
      const float4* w2p = (const float4*)(wt + (size_t)(2 * 9 + tap) * DIM + icg * 32);
      #pragma unroll
      for (int q = 0; q < 8; q++) {
        float4 qv = crow[q];
        float4 wa = w0p[q];
        a0 = fmaf(qv.x, wa.x, a0); a0 = fmaf(qv.y, wa.y, a0);
        a0 = fmaf(qv.z, wa.z, a0); a0 = fmaf(qv.w, wa.w, a0);
        float4 wb = w1p[q];
        a1 = fmaf(qv.x, wb.x, a1); a1 = fmaf(qv.y, wb.y, a1);
        a1 = fmaf(qv.z, wb.z, a1); a1 = fmaf(qv.w, wb.w, a1);
        float4 wcv = w2p[q];
        a2 = fmaf(qv.x, wcv.x, a2); a2 = fmaf(qv.y, wcv.y, a2);
        a2 = fmaf(qv.z, wcv.z, a2); a2 = fmaf(qv.w, wcv.w, a2);
      }
    }
  }
  __shared__ float red[3][32][8];
  red[0][x][icg] = a0; red[1][x][icg] = a1; red[2][x][icg] = a2;
  __syncthreads();
  if (t < 96) {
    int oc = t >> 5, xo = t & 31;
    float sum = 0.f;
    #pragma unroll
    for (int k = 0; k < 8; k++) sum += red[oc][xo][k];
    sum += bias[oc];
    sum = (sum + 1.0f) * 0.5f;
    sum = fminf(fmaxf(sum, 0.0f), 1.0f);
    out[((size_t)(b * 3 + oc) * 32 + y) * 32 + xo] = sum;
  }
}

extern "C" void kernel_launch(void* const* d_in, const int* in_sizes, int n_in,
                              void* d_out, int out_size, void* d_ws, size_t ws_size,
                              hipStream_t stream) {
  const float* latent = (const float*)d_in[0];   // [4,256,32,32]
  const float* cb     = (const float*)d_in[1];   // [16384,256]
  const float* dec_w  = (const float*)d_in[2];   // [3,256,3,3]
  const float* dec_b  = (const float*)d_in[3];   // [3]
  float* out = (float*)d_out;                    // [4,3,32,32]

  char* ws = (char*)d_ws;
  u64*   partial = (u64*)ws;                      // 512 KB [4096][16]
  float* cnorm   = (float*)(ws + 0x080000);       // 64 KB
  float* wt      = (float*)(ws + 0x094000);       // 27 KB
  u16*   xfrag   = (u16*)  (ws + 0x100000);       // 4 MB
  u16*   bfrag   = (u16*)  (ws + 0x800000);       // 16 MB (ends at 24 MB)

  k_prep<<<dim3(5403), dim3(256), 0, stream>>>(cb, latent, dec_w, bfrag, xfrag, cnorm, wt);
  k_vq  <<<dim3(256),  dim3(512), 0, stream>>>(xfrag, bfrag, cnorm, partial);
  k_conv<<<dim3(32, 4), dim3(256), 0, stream>>>(partial, latent, cb, wt, dec_b, out);
}

// Round 9
// 191.716 us; speedup vs baseline: 2.2449x; 1.1316x over previous
//
#include <hip/hip_runtime.h>
#include <hip/hip_bf16.h>
#include <stdint.h>

#define P_TOT   4096
#define N_CODE  16384
#define DIM     256
#define HW      1024
#define CHW     262144
#define NBLK    16        // 16384 / 1024 codes per wg-chunk

typedef unsigned long long u64;
typedef unsigned short u16;
typedef __attribute__((ext_vector_type(4))) float f32x4;
typedef __attribute__((ext_vector_type(8))) short bf16x8;
typedef __attribute__((ext_vector_type(8))) unsigned short ushort8;

#define FENCE() asm volatile("" ::: "memory")
#define BAR()   __builtin_amdgcn_s_barrier()
#define VM(n)   asm volatile("s_waitcnt vmcnt(" #n ")" ::: "memory")

__device__ __forceinline__ unsigned int mono(float f) {
  unsigned int u = __float_as_uint(f);
  return (u & 0x80000000u) ? ~u : (u | 0x80000000u);
}
__device__ __forceinline__ u16 f2bf(float f) {
  __hip_bfloat16 h = __float2bfloat16(f);
  return *(u16*)&h;
}
__device__ __forceinline__ float bf2f(u16 b) {
  __hip_bfloat16 h = *(__hip_bfloat16*)&b;
  return __bfloat162float(h);
}
__device__ __forceinline__ void gload16(const void* g, void* l) {
  __builtin_amdgcn_global_load_lds(
      (const __attribute__((address_space(1))) unsigned int*)g,
      (__attribute__((address_space(3))) unsigned int*)l, 16, 0, 0);
}

// ================== merged prep: split_cb | split_x | cnorm | wt ==================
// bfrag unit [(nb*8+kt)*4+bq] of 4096 u16: [h(2)][s(4)][row64][8elem]
// xfrag unit [(mbO*8+kt)*4+aq] same internal layout (rows = pixels)
__global__ __launch_bounds__(256) void k_prep(const float* __restrict__ cb,
                                              const float* __restrict__ latent,
                                              const float* __restrict__ dec_w,
                                              u16* __restrict__ bfrag,
                                              u16* __restrict__ xfrag,
                                              float* __restrict__ cnorm,
                                              float* __restrict__ wt) {
  __shared__ float ls[64][68];
  int bid = blockIdx.x;
  int t = threadIdx.x;
  if (bid < 1024) {
    int blk = bid;                   // nb(64) x bq(4) x kp(4)
    int kp = blk & 3, bq = (blk >> 2) & 3, nb = blk >> 4;
    int code0 = nb * 256 + bq * 64;
    int k0 = kp * 64;
    int lr = t >> 4, lc = (t & 15) * 4;
    #pragma unroll
    for (int pss = 0; pss < 4; ++pss) {
      int row = pss * 16 + lr;
      float4 v = *(const float4*)&cb[(size_t)(code0 + row) * DIM + k0 + lc];
      ls[row][lc] = v.x; ls[row][lc + 1] = v.y; ls[row][lc + 2] = v.z; ls[row][lc + 3] = v.w;
    }
    __syncthreads();
    int row64 = t & 63, g = t >> 6;
    #pragma unroll
    for (int it = 0; it < 4; ++it) {
      int combo = it * 4 + g;        // kt2*8 + s*2 + h
      int kt2 = combo >> 3, s = (combo >> 1) & 3, h = combo & 1;
      int kt = kp * 2 + kt2;
      ushort8 o;
      #pragma unroll
      for (int e = 0; e < 8; ++e) {
        float x = ls[row64][kt2 * 32 + s * 8 + e];
        u16 hi = f2bf(x);
        o[e] = h ? f2bf(x - bf2f(hi)) : hi;
      }
      size_t unitIdx = (size_t)(nb * 8 + kt) * 4 + bq;
      *(ushort8*)&bfrag[unitIdx * 4096 + (size_t)((h * 4 + s) * 64 + row64) * 8] = o;
    }
  } else if (bid < 1280) {
    int blk = bid - 1024;            // rowblk(64) x kp(4)
    int kp = blk & 3, rowblk = blk >> 2;
    int g0 = rowblk * 64;
    int b = g0 >> 10, hw0 = g0 & 1023;
    int c0 = kp * 64;
    int ch = t >> 4, px4 = (t & 15) * 4;
    #pragma unroll
    for (int pss = 0; pss < 4; ++pss) {
      int c = pss * 16 + ch;
      float4 v = *(const float4*)&latent[(size_t)b * CHW + (size_t)(c0 + c) * HW + hw0 + px4];
      ls[px4 + 0][c] = v.x; ls[px4 + 1][c] = v.y; ls[px4 + 2][c] = v.z; ls[px4 + 3][c] = v.w;
    }
    __syncthreads();
    int row64 = t & 63, g = t >> 6;
    #pragma unroll
    for (int it = 0; it < 4; ++it) {
      int combo = it * 4 + g;
      int kt2 = combo >> 3, s = (combo >> 1) & 3, h = combo & 1;
      int kt = kp * 2 + kt2;
      ushort8 o;
      #pragma unroll
      for (int e = 0; e < 8; ++e) {
        float x = ls[row64][kt2 * 32 + s * 8 + e];
        u16 hi = f2bf(x);
        o[e] = h ? f2bf(x - bf2f(hi)) : hi;
      }
      int mbO = rowblk >> 2, aq = rowblk & 3;
      size_t unitIdx = (size_t)(mbO * 8 + kt) * 4 + aq;
      *(ushort8*)&xfrag[unitIdx * 4096 + (size_t)((h * 4 + s) * 64 + row64) * 8] = o;
    }
  } else if (bid < 5376) {
    int code = (bid - 1280) * 4 + (t >> 6);
    int lane = t & 63;
    float4 v = ((const float4*)(cb + (size_t)code * DIM))[lane];
    float sv = fmaf(v.x, v.x, fmaf(v.y, v.y, fmaf(v.z, v.z, v.w * v.w)));
    #pragma unroll
    for (int off = 32; off; off >>= 1) sv += __shfl_down(sv, off, 64);
    if (lane == 0) cnorm[code] = sv;
  } else {
    int e = (bid - 5376) * 256 + t;
    if (e < 6912) {
      int ic = e & 255; int r = e >> 8;
      int kx = r % 3; r /= 3; int ky = r % 3; int oc = r / 3;
      wt[e] = dec_w[((oc * 256 + ic) * 3 + ky) * 3 + kx];
    }
  }
}

// ================== main VQ: 256x256 tile, ONE barrier per K-tile, 32-tile pipeline ==================
// Grid 256 = 1 wg/CU. Each wg: 4 nb-panels (1024 codes) x 8 K-tiles.
__global__ __launch_bounds__(512, 2) void k_vq(const u16* __restrict__ xfrag,
                                               const u16* __restrict__ bfrag,
                                               const float* __restrict__ cnorm,
                                               u64* __restrict__ partial) {
  __shared__ u16 lds[2][2][4][4096];   // [buf][A/B][unit][8KB] = 128 KiB
  __shared__ float cnl[1024];

  int bid = blockIdx.x;                // 256 wgs
  int xcd = bid & 7, ix = bid >> 3;    // 32 per XCD
  int nbc = xcd * 2 + (ix >> 4);       // 0..15 (1024-code chunk; 2 chunks/XCD -> 2MB B in L2)
  int mb  = ix & 15;                   // 0..15 (256-row X block)

  int tid = threadIdx.x, lane = tid & 63, w = tid >> 6;
  int fr = lane & 15, s = lane >> 4;
  int aq = w >> 1;
  int rbase = (w & 1) * 32;
  int tid8 = tid * 8;

  const u16* Xb = xfrag + (size_t)mb * 32 * 4096;    // units kt*4+aq
  const u16* Bb = bfrag + (size_t)nbc * 128 * 4096;  // 32 tiles x 4 units

  // cnorm chunk -> LDS (full drain via __syncthreads before staging begins)
  cnl[tid]       = cnorm[nbc * 1024 + tid];
  cnl[tid + 512] = cnorm[nbc * 1024 + 512 + tid];
  __syncthreads();

  // ---- prologue: stage tile 0 fully ----
  #pragma unroll
  for (int r = 0; r < 4; ++r) gload16(Xb + (size_t)r * 4096 + tid8, &lds[0][0][r][0] + tid8);
  #pragma unroll
  for (int r = 0; r < 4; ++r) gload16(Bb + (size_t)r * 4096 + tid8, &lds[0][1][r][0] + tid8);
  VM(0); BAR(); FENCE();

  f32x4 acc[2][16] = {};
  u64 best[4]  = {~0ull, ~0ull, ~0ull, ~0ull};   // best for m=0 rows
  u64 best2[4] = {~0ull, ~0ull, ~0ull, ~0ull};   // best for m=1 rows
  bf16x8 ah[2], al[2], bh[4], bl[4];

  #define READ_A(LA)                                                          \
    _Pragma("unroll")                                                         \
    for (int m = 0; m < 2; ++m) {                                             \
      ah[m] = *(const bf16x8*)&(LA)[aq * 4096 + (size_t)((0 + s) * 64 + rbase + m * 16 + fr) * 8]; \
      al[m] = *(const bf16x8*)&(LA)[aq * 4096 + (size_t)((4 + s) * 64 + rbase + m * 16 + fr) * 8]; \
    }
  #define READ_B(LB, q)                                                       \
    _Pragma("unroll")                                                         \
    for (int j = 0; j < 4; ++j) {                                             \
      bh[j] = *(const bf16x8*)&(LB)[(q) * 4096 + (size_t)((0 + s) * 64 + j * 16 + fr) * 8]; \
      bl[j] = *(const bf16x8*)&(LB)[(q) * 4096 + (size_t)((4 + s) * 64 + j * 16 + fr) * 8]; \
    }
  #define MFMAQ(q)                                                            \
    __builtin_amdgcn_s_setprio(1);                                            \
    _Pragma("unroll")                                                         \
    for (int m = 0; m < 2; ++m) {                                             \
      _Pragma("unroll")                                                       \
      for (int j = 0; j < 4; ++j)                                             \
        acc[m][(q) * 4 + j] = __builtin_amdgcn_mfma_f32_16x16x32_bf16(ah[m], bh[j], acc[m][(q) * 4 + j], 0, 0, 0); \
    }                                                                         \
    _Pragma("unroll")                                                         \
    for (int m = 0; m < 2; ++m) {                                             \
      _Pragma("unroll")                                                       \
      for (int j = 0; j < 4; ++j)                                             \
        acc[m][(q) * 4 + j] = __builtin_amdgcn_mfma_f32_16x16x32_bf16(ah[m], bl[j], acc[m][(q) * 4 + j], 0, 0, 0); \
    }                                                                         \
    _Pragma("unroll")                                                         \
    for (int m = 0; m < 2; ++m) {                                             \
      _Pragma("unroll")                                                       \
      for (int j = 0; j < 4; ++j)                                             \
        acc[m][(q) * 4 + j] = __builtin_amdgcn_mfma_f32_16x16x32_bf16(al[m], bh[j], acc[m][(q) * 4 + j], 0, 0, 0); \
    }                                                                         \
    __builtin_amdgcn_s_setprio(0);
  #define FOLD(pp)                                                            \
    _Pragma("unroll")                                                         \
    for (int n = 0; n < 16; ++n) {                                            \
      float cnv = cnl[(pp) * 256 + n * 16 + fr];                              \
      unsigned code = (unsigned)(nbc * 1024 + (pp) * 256 + n * 16 + fr);      \
      _Pragma("unroll")                                                       \
      for (int r = 0; r < 4; ++r) {                                           \
        float v0 = fmaf(-2.0f, acc[0][n][r], cnv);                            \
        u64 k0 = ((u64)mono(v0) << 32) | code;                                \
        if (k0 < best[r]) best[r] = k0;                                       \
        acc[0][n][r] = 0.0f;                                                  \
        float v1 = fmaf(-2.0f, acc[1][n][r], cnv);                            \
        u64 k1 = ((u64)mono(v1) << 32) | code;                                \
        if (k1 < best2[r]) best2[r] = k1;                                     \
        acc[1][n][r] = 0.0f;                                                  \
      }                                                                       \
    }

  // ---- 32 K-tiles (4 panels x 8), ONE barrier-pair each ----
  // Hazard audit (single BAR/tile): by the time a wave passes tile-tt's BAR,
  // its tt ds_reads are retired (consumed by MFMA via compiler lgkm waits), so
  // tt+1 staging into the opposite buffer can't corrupt in-flight reads; each
  // wave's VM(0) before BAR + all-arrive semantics => staged data visible.
  // VM(0) lands ~3700 cyc after issue (B chunk L2-resident ~300 cyc) => free.
  #pragma unroll 1
  for (int tt = 0; tt < 32; ++tt) {
    const int cur = tt & 1, nxt = cur ^ 1;
    const int kt = tt & 7;
    u16* LA = &lds[cur][0][0][0];
    u16* LB = &lds[cur][1][0][0];
    const u16* SA = Xb + (size_t)((tt + 1) & 7) * 16384;
    const u16* SB = Bb + (size_t)(tt + 1) * 16384;
    const bool stage = (tt < 31);
    READ_A(LA); READ_B(LB, 0);
    if (stage) {
      #pragma unroll
      for (int r = 0; r < 4; ++r) gload16(SA + (size_t)r * 4096 + tid8, &lds[nxt][0][r][0] + tid8);
      #pragma unroll
      for (int r = 0; r < 4; ++r) gload16(SB + (size_t)r * 4096 + tid8, &lds[nxt][1][r][0] + tid8);
    }
    MFMAQ(0);
    READ_B(LB, 1);
    MFMAQ(1);
    READ_B(LB, 2);
    MFMAQ(2);
    READ_B(LB, 3);
    MFMAQ(3);
    if (kt == 7) { FOLD(tt >> 3); }
    VM(0);
    BAR(); FENCE();
  }

  // ---- reduce over fr lanes (codes), write per-row minimum ----
  #pragma unroll
  for (int d = 1; d < 16; d <<= 1) {
    #pragma unroll
    for (int r = 0; r < 4; ++r) {
      u64 o = __shfl_xor(best[r], d, 64);
      if (o < best[r]) best[r] = o;
      u64 o2 = __shfl_xor(best2[r], d, 64);
      if (o2 < best2[r]) best2[r] = o2;
    }
  }
  if (fr == 0) {
    int rowb = mb * 256 + w * 32 + s * 4;
    #pragma unroll
    for (int r = 0; r < 4; ++r) {
      partial[(size_t)(rowb + r) * NBLK + nbc] = best[r];
      partial[(size_t)(rowb + 16 + r) * NBLK + nbc] = best2[r];
    }
  }
}

// ---- per-pixel top-2 reduce + exact fp64 refinement (1 wave/pixel) ----
__global__ __launch_bounds__(256) void k_idx(const u64* __restrict__ partial,
                                             const float* __restrict__ latent,
                                             const float* __restrict__ cb,
                                             int* __restrict__ idxo) {
  int p = (blockIdx.x * 256 + threadIdx.x) >> 6;   // pixel id, 1 wave each
  int lane = threadIdx.x & 63;
  u64 v = (lane < NBLK) ? partial[(size_t)p * NBLK + lane] : ~0ull;
  u64 m1 = v;
  #pragma unroll
  for (int d = 1; d < 64; d <<= 1) { u64 o = __shfl_xor(m1, d, 64); if (o < m1) m1 = o; }
  u64 vv = (v == m1) ? ~0ull : v;
  u64 m2 = vv;
  #pragma unroll
  for (int d = 1; d < 64; d <<= 1) { u64 o = __shfl_xor(m2, d, 64); if (o < m2) m2 = o; }
  int n1 = (int)(m1 & 0xFFFFFFFFull);
  int n2 = (int)(m2 & 0xFFFFFFFFull);

  int b = p >> 10, hw = p & 1023;
  const float* xb = latent + (size_t)b * CHW + hw;
  double d1 = 0.0, d2 = 0.0;
  #pragma unroll
  for (int q = 0; q < 4; ++q) {
    int c = lane * 4 + q;
    double xv = (double)xb[(size_t)c * HW];
    double e1 = xv - (double)cb[(size_t)n1 * DIM + c]; d1 += e1 * e1;
    double e2 = xv - (double)cb[(size_t)n2 * DIM + c]; d2 += e2 * e2;
  }
  #pragma unroll
  for (int d = 32; d; d >>= 1) {
    d1 += __shfl_down(d1, d, 64);
    d2 += __shfl_down(d2, d, 64);
  }
  if (lane == 0) {
    idxo[p] = (d2 < d1 || (d2 == d1 && n2 < n1)) ? n2 : n1;
  }
}

// ---- gather + 3x3 conv + bias + (x+1)*0.5 + clamp ----
__global__ __launch_bounds__(256) void k_conv(const int* __restrict__ idxo,
                                              const float* __restrict__ cb,
                                              const float* __restrict__ wt,
                                              const float* __restrict__ bias,
                                              float* __restrict__ out) {
  __shared__ int idxl[3][32];
  int y = blockIdx.x, b = blockIdx.y;
  int t = threadIdx.x;
  if (t < 96) {
    int r = t >> 5, px = t & 31;
    int yy = min(max(y + r - 1, 0), 31);
    idxl[r][px] = idxo[b * HW + yy * 32 + px];
  }
  __syncthreads();

  int x = t & 31, icg = t >> 5;
  float a0 = 0.f, a1 = 0.f, a2 = 0.f;
  #pragma unroll
  for (int dy = -1; dy <= 1; dy++) {
    int yy = y + dy;
    if (yy < 0 || yy >= 32) continue;
    #pragma unroll
    for (int dx = -1; dx <= 1; dx++) {
      int xx = x + dx;
      if (xx < 0 || xx >= 32) continue;
      int n = idxl[dy + 1][xx];
      const float4* crow = (const float4*)(cb + (size_t)n * DIM + icg * 32);
      int tap = (dy + 1) * 3 + (dx + 1);
      const float4* w0p = (const float4*)(wt + (size_t)(0 * 9 + tap) * DIM + icg * 32);
      const float4* w1p = (const float4*)(wt + (size_t)(1 * 9 + tap) * DIM + icg * 32);
      const float4* w2p = (const float4*)(wt + (size_t)(2 * 9 + tap) * DIM + icg * 32);
      #pragma unroll
      for (int q = 0; q < 8; q++) {
        float4 qv = crow[q];
        float4 wa = w0p[q];
        a0 = fmaf(qv.x, wa.x, a0); a0 = fmaf(qv.y, wa.y, a0);
        a0 = fmaf(qv.z, wa.z, a0); a0 = fmaf(qv.w, wa.w, a0);
        float4 wb = w1p[q];
        a1 = fmaf(qv.x, wb.x, a1); a1 = fmaf(qv.y, wb.y, a1);
        a1 = fmaf(qv.z, wb.z, a1); a1 = fmaf(qv.w, wb.w, a1);
        float4 wcv = w2p[q];
        a2 = fmaf(qv.x, wcv.x, a2); a2 = fmaf(qv.y, wcv.y, a2);
        a2 = fmaf(qv.z, wcv.z, a2); a2 = fmaf(qv.w, wcv.w, a2);
      }
    }
  }
  __shared__ float red[3][32][8];
  red[0][x][icg] = a0; red[1][x][icg] = a1; red[2][x][icg] = a2;
  __syncthreads();
  if (t < 96) {
    int oc = t >> 5, xo = t & 31;
    float sum = 0.f;
    #pragma unroll
    for (int k = 0; k < 8; k++) sum += red[oc][xo][k];
    sum += bias[oc];
    sum = (sum + 1.0f) * 0.5f;
    sum = fminf(fmaxf(sum, 0.0f), 1.0f);
    out[((size_t)(b * 3 + oc) * 32 + y) * 32 + xo] = sum;
  }
}

extern "C" void kernel_launch(void* const* d_in, const int* in_sizes, int n_in,
                              void* d_out, int out_size, void* d_ws, size_t ws_size,
                              hipStream_t stream) {
  const float* latent = (const float*)d_in[0];   // [4,256,32,32]
  const float* cb     = (const float*)d_in[1];   // [16384,256]
  const float* dec_w  = (const float*)d_in[2];   // [3,256,3,3]
  const float* dec_b  = (const float*)d_in[3];   // [3]
  float* out = (float*)d_out;                    // [4,3,32,32]

  char* ws = (char*)d_ws;
  u64*   partial = (u64*)ws;                      // 512 KB [4096][16]
  float* cnorm   = (float*)(ws + 0x080000);       // 64 KB
  int*   idx     = (int*)  (ws + 0x090000);       // 16 KB
  float* wt      = (float*)(ws + 0x094000);       // 27 KB
  u16*   xfrag   = (u16*)  (ws + 0x100000);       // 4 MB
  u16*   bfrag   = (u16*)  (ws + 0x800000);       // 16 MB (ends at 24 MB)

  k_prep<<<dim3(5403), dim3(256), 0, stream>>>(cb, latent, dec_w, bfrag, xfrag, cnorm, wt);
  k_vq  <<<dim3(256),  dim3(512), 0, stream>>>(xfrag, bfrag, cnorm, partial);
  k_idx <<<dim3(1024), dim3(256), 0, stream>>>(partial, latent, cb, idx);
  k_conv<<<dim3(32, 4), dim3(256), 0, stream>>>(idx, cb, wt, dec_b, out);
}